// Round 11
// baseline (63.735 us; speedup 1.0000x reference)
//
#include <hip/hip_runtime.h>
#include <stdint.h>
#include <math.h>

#define N     500
#define DIN   100
#define DE    200
#define DOUT  100
#define AROW  (2*DIN + DE)        // 400
#define SLOPE 0.2f

#define JCH   2                   // j-chunks per row i
#define CROWS 250                 // 500 / 2
#define SLOTS 256                 // CROWS padded to mult of 8
#define KP    512                 // Pbuf padded row length (j)
#define BK    720                 // Bcat row length: 512 (j) + 208 (d pad)
#define DEP   208                 // padded DE (f32 gsum stride)
#define GZF   104000              // 500*208 floats to zero

typedef __attribute__((ext_vector_type(8)))  short short8;
typedef __attribute__((ext_vector_type(16))) float f32x16;

static __device__ __forceinline__ unsigned short f2bf(float f) {
  union { float f; uint32_t u; } v; v.f = f;
  uint32_t r = (v.u + 0x7FFFu + ((v.u >> 16) & 1u)) >> 16;   // RNE
  return (unsigned short)r;
}

// ---------- K1: merged setup ----------
__global__ __launch_bounds__(256)
void setup_kernel(const float* __restrict__ R, const float* __restrict__ A,
                  const float* __restrict__ a2,
                  float* __restrict__ src, float* __restrict__ ssrc,
                  float* __restrict__ sdst, float* __restrict__ wv,
                  unsigned short* __restrict__ Bcat, unsigned short* __restrict__ Pbuf,
                  float* __restrict__ gsum, float* __restrict__ Zsum) {
  int b = blockIdx.x, t = threadIdx.x;
  if (b < N) {
    int i = b;
    __shared__ float rrow[DIN];
    __shared__ float sred[4];
    if (t < DIN) rrow[t] = R[i * DIN + t];
    if (t < KP - N) Pbuf[i * KP + N + t] = 0;          // zero j-pad 500..511
    __syncthreads();
    int o = -1; bool isSrc = false;
    if (t < DOUT) { o = t; isSrc = true; }
    else if (t >= 128 && t < 128 + DOUT) { o = t - 128; }
    float val = 0.f;
    if (o >= 0) {
      const float* arow = A + o * AROW + (isSrc ? 0 : DIN);
      #pragma unroll 4
      for (int d = 0; d < DIN; ++d) val += rrow[d] * arow[d];
      if (isSrc) src[i * DOUT + o] = val;
      else       Bcat[o * BK + i] = f2bf(val);         // B[k=j=i][n=o] = dst[j,o]
    }
    float red = (o >= 0) ? val * a2[o] : 0.f;
    #pragma unroll
    for (int k = 1; k < 64; k <<= 1) red += __shfl_xor(red, k, 64);
    if ((t & 63) == 0) sred[t >> 6] = red;
    __syncthreads();
    if (t == 0)   ssrc[i] = sred[0] + sred[1];
    if (t == 128) sdst[i] = sred[2] + sred[3];
  } else if (b == N) {
    if (t < DE) {
      float s = 0.f;
      for (int o = 0; o < DOUT; ++o) s += A[o * AROW + 2 * DIN + t] * a2[o];
      wv[t] = s;
    }
  } else if (b <= N + DOUT) {
    int o = b - (N + 1);
    if (t < DE) Bcat[o * BK + KP + t] = f2bf(A[o * AROW + 2 * DIN + t]);
    if (t < KP - N) Bcat[o * BK + N + t] = 0;                                 // j-pad
    if (t >= 32 && t < 32 + (BK - KP - DE)) Bcat[o * BK + KP + DE + (t - 32)] = 0; // d-pad
  } else if (b <= 702) {
    int off = (b - 601) * 1024 + t * 4;
    if (off < GZF) *(float4*)(gsum + off) = make_float4(0.f, 0.f, 0.f, 0.f);
  } else {
    if (t < 125) *(float4*)(Zsum + t * 4) = make_float4(0.f, 0.f, 0.f, 0.f);
  }
}

// ---------- K2: FULL-STREAM pass over E (no gather; sentinel-masked) ----------
__global__ __launch_bounds__(256, 4)
void passA(const float* __restrict__ E, const int* __restrict__ adj,
           const float* __restrict__ ssrcA, const float* __restrict__ sdstA,
           const float* __restrict__ wv,
           unsigned short* __restrict__ Pbuf,
           float* __restrict__ gsum, float* __restrict__ Zsum) {
  __shared__ float bias[SLOTS];         // ssrc_i + sdst[j], or -1e30 sentinel
  __shared__ float gl[4][200];
  __shared__ float zl[4];

  int bid = blockIdx.x;
  int i = bid >> 1, c = bid & 1;
  int jbeg = c * CROWS;
  int t = threadIdx.x, wid = t >> 6, lane = t & 63;
  int ll = lane & 31;                   // lane-in-group
  int grp = lane >> 5;                  // 0 = row A, 1 = row B

  float ssrc_i = ssrcA[i];
  {
    int j = jbeg + t;
    bias[t] = (t < CROWS && adj[(size_t)i * N + j] > 0) ? (ssrc_i + sdstA[j])
                                                        : -1e30f;   // p -> 0
  }
  __syncthreads();

  // per-lane w slice: elems [8ll .. 8ll+7]
  float4 wa = make_float4(0.f, 0.f, 0.f, 0.f), wb = wa;
  if (ll < 25) {
    wa = *(const float4*)(wv + ll * 8);
    wb = *(const float4*)(wv + ll * 8 + 4);
  }

  float g1x = 0.f, g1y = 0.f, g1z = 0.f, g1w = 0.f;   // elems 8ll+0..3
  float g2x = 0.f, g2y = 0.f, g2z = 0.f, g2w = 0.f;   // elems 8ll+4..7
  float Z = 0.f;
  const float* Erow = E + (size_t)i * N * DE;

  // main: 8 consecutive rows (4 row-pairs) per wave per iteration — sequential HBM stream
  for (int base = wid * 8; base < SLOTS; base += 32) {
    #pragma unroll
    for (int r = 0; r < 4; ++r) {
      int slot = base + 2 * r + grp;                  // per-lane: group picks row
      int j = jbeg + slot;
      float bi = bias[slot];
      float4 ev1 = make_float4(0.f, 0.f, 0.f, 0.f), ev2 = ev1;
      if (ll < 25 && slot < CROWS) {
        const float* rp = Erow + (size_t)j * DE + ll * 8;
        ev1 = *(const float4*)(rp);
        ev2 = *(const float4*)(rp + 4);
      }
      float d = ev1.x * wa.x + ev1.y * wa.y + ev1.z * wa.z + ev1.w * wa.w
              + ev2.x * wb.x + ev2.y * wb.y + ev2.z * wb.z + ev2.w * wb.w;
      d += __shfl_xor(d, 1);  d += __shfl_xor(d, 2);  d += __shfl_xor(d, 4);
      d += __shfl_xor(d, 8);  d += __shfl_xor(d, 16);      // uniform within group
      float s = bi + d;
      s = s > 0.f ? s : SLOPE * s;
      float p = __expf(s);                                 // exactly 0 for masked/sentinel
      Z += p;
      g1x += p * ev1.x; g1y += p * ev1.y; g1z += p * ev1.z; g1w += p * ev1.w;
      g2x += p * ev2.x; g2y += p * ev2.y; g2z += p * ev2.z; g2w += p * ev2.w;
      if (ll == 0 && slot < CROWS) Pbuf[i * KP + j] = f2bf(p);
    }
  }

  // merge the two groups (A+B) once
  g1x += __shfl_xor(g1x, 32); g1y += __shfl_xor(g1y, 32);
  g1z += __shfl_xor(g1z, 32); g1w += __shfl_xor(g1w, 32);
  g2x += __shfl_xor(g2x, 32); g2y += __shfl_xor(g2y, 32);
  g2z += __shfl_xor(g2z, 32); g2w += __shfl_xor(g2w, 32);
  Z += __shfl_xor(Z, 32);

  if (lane < 25) {
    float* gp = &gl[wid][lane * 8];
    gp[0] = g1x; gp[1] = g1y; gp[2] = g1z; gp[3] = g1w;
    gp[4] = g2x; gp[5] = g2y; gp[6] = g2z; gp[7] = g2w;
  }
  if (lane == 0) zl[wid] = Z;
  __syncthreads();
  if (t < 200) {
    float s = gl[0][t] + gl[1][t] + gl[2][t] + gl[3][t];
    atomicAdd(gsum + (size_t)i * DEP + t, s);
  }
  if (t == 200) atomicAdd(Zsum + i, zl[0] + zl[1] + zl[2] + zl[3]);
}

// ---------- K3: combine — [P | g] @ [dst ; a_ent^T] via MFMA (dual acc chains) ----------
__global__ __launch_bounds__(64)
void combine_kernel(const float* __restrict__ src,
                    const unsigned short* __restrict__ Pbuf,
                    const unsigned short* __restrict__ Bcat,
                    const float* __restrict__ gsum,
                    const float* __restrict__ Zsum,
                    float* __restrict__ out) {
  int b = blockIdx.x;
  int i0 = (b >> 2) * 32;
  int ow = b & 3;
  int t = threadIdx.x;                  // 0..63
  int c31 = t & 31, hi = t >> 5;
  int o = ow * 32 + c31;
  int arow = i0 + c31; if (arow > N - 1) arow = N - 1;

  const unsigned short* Prow = Pbuf + (size_t)arow * KP;
  const float* grow = gsum + (size_t)arow * DEP;

  f32x16 acc0 = {}, acc1 = {};
  #pragma unroll
  for (int ks = 0; ks < 45; ++ks) {
    short8 a, bf;
    if (ks < 32) {
      a = *(const short8*)(Prow + ks * 16 + hi * 8);
    } else {
      int d0 = (ks - 32) * 16 + hi * 8;
      float4 ga = *(const float4*)(grow + d0);
      float4 gb = *(const float4*)(grow + d0 + 4);
      a[0] = (short)f2bf(ga.x); a[1] = (short)f2bf(ga.y);
      a[2] = (short)f2bf(ga.z); a[3] = (short)f2bf(ga.w);
      a[4] = (short)f2bf(gb.x); a[5] = (short)f2bf(gb.y);
      a[6] = (short)f2bf(gb.z); a[7] = (short)f2bf(gb.w);
    }
    if (o < DOUT) bf = *(const short8*)(Bcat + (size_t)o * BK + ks * 16 + hi * 8);
    else { short8 zz = {}; bf = zz; }
    if (ks & 1) acc1 = __builtin_amdgcn_mfma_f32_32x32x16_bf16(a, bf, acc1, 0, 0, 0);
    else        acc0 = __builtin_amdgcn_mfma_f32_32x32x16_bf16(a, bf, acc0, 0, 0, 0);
  }

  if (o < DOUT) {
    #pragma unroll
    for (int r = 0; r < 16; ++r) {
      int row = (r & 3) + 8 * (r >> 2) + 4 * hi;
      int i = i0 + row;
      if (i < N) {
        float h = src[i * DOUT + o] + (acc0[r] + acc1[r]) / Zsum[i];
        out[i * DOUT + o] = h > 0.f ? h : expm1f(h);
      }
    }
  }
}

extern "C" void kernel_launch(void* const* d_in, const int* in_sizes, int n_in,
                              void* d_out, int out_size, void* d_ws, size_t ws_size,
                              hipStream_t stream) {
  const float* R   = (const float*)d_in[0];
  const float* E   = (const float*)d_in[1];
  const int*   adj = (const int*)d_in[2];
  const float* A   = (const float*)d_in[3];
  const float* a2  = (const float*)d_in[4];
  float* out = (float*)d_out;

  char* wsb = (char*)d_ws;
  float*          src  = (float*)(wsb + 0);                // 200,000 B
  float*          ssrc = (float*)(wsb + 200000);           //   2,000 B
  float*          sdst = (float*)(wsb + 202000);           //   2,000 B
  float*          wv   = (float*)(wsb + 204000);           //     800 B
  unsigned short* Bcat = (unsigned short*)(wsb + 204800);  // 144,000 B
  unsigned short* Pbuf = (unsigned short*)(wsb + 348800);  // 512,000 B
  float*          gsum = (float*)(wsb + 860800);           // 416,000 B (f32, atomic)
  float*          Zsum = (float*)(wsb + 1276800);          //   2,000 B

  setup_kernel<<<704, 256, 0, stream>>>(R, A, a2, src, ssrc, sdst, wv, Bcat, Pbuf, gsum, Zsum);
  passA<<<N * JCH, 256, 0, stream>>>(E, adj, ssrc, sdst, wv, Pbuf, gsum, Zsum);
  combine_kernel<<<64, 64, 0, stream>>>(src, Pbuf, Bcat, gsum, Zsum, out);
}

// Round 13
// 59.092 us; speedup vs baseline: 1.0786x; 1.0786x over previous
//
#include <hip/hip_runtime.h>
#include <stdint.h>
#include <math.h>

#define N     500
#define DIN   100
#define DE    200
#define DOUT  100
#define AROW  (2*DIN + DE)        // 400
#define SLOPE 0.2f

#define JCH   2                   // j-chunks per row i
#define CROWS 250                 // 500 / 2
#define KP    512                 // Pbuf padded row length (j)
#define BK    720                 // Bcat row length: 512 (j) + 208 (d pad)
#define DEP   208                 // padded DE (f32 gsum stride)
#define GZF   104000              // 500*208 floats to zero

typedef __attribute__((ext_vector_type(8)))  short short8;
typedef __attribute__((ext_vector_type(16))) float f32x16;
typedef __attribute__((ext_vector_type(4)))  float f32x4;   // native vector: NT-load legal

static __device__ __forceinline__ unsigned short f2bf(float f) {
  union { float f; uint32_t u; } v; v.f = f;
  uint32_t r = (v.u + 0x7FFFu + ((v.u >> 16) & 1u)) >> 16;   // RNE
  return (unsigned short)r;
}

// ---------- K1: merged setup ----------
__global__ __launch_bounds__(256)
void setup_kernel(const float* __restrict__ R, const float* __restrict__ A,
                  const float* __restrict__ a2,
                  float* __restrict__ src, float* __restrict__ ssrc,
                  float* __restrict__ sdst, float* __restrict__ wv,
                  unsigned short* __restrict__ Bcat, unsigned short* __restrict__ Pbuf,
                  float* __restrict__ gsum, float* __restrict__ Zsum) {
  int b = blockIdx.x, t = threadIdx.x;
  if (b < N) {
    int i = b;
    __shared__ float rrow[DIN];
    __shared__ float sred[4];
    if (t < DIN) rrow[t] = R[i * DIN + t];
    if (t < KP - N) Pbuf[i * KP + N + t] = 0;          // zero j-pad 500..511
    __syncthreads();
    int o = -1; bool isSrc = false;
    if (t < DOUT) { o = t; isSrc = true; }
    else if (t >= 128 && t < 128 + DOUT) { o = t - 128; }
    float val = 0.f;
    if (o >= 0) {
      const float* arow = A + o * AROW + (isSrc ? 0 : DIN);
      #pragma unroll 4
      for (int d = 0; d < DIN; ++d) val += rrow[d] * arow[d];
      if (isSrc) src[i * DOUT + o] = val;
      else       Bcat[o * BK + i] = f2bf(val);         // B[k=j=i][n=o] = dst[j,o]
    }
    float red = (o >= 0) ? val * a2[o] : 0.f;
    #pragma unroll
    for (int k = 1; k < 64; k <<= 1) red += __shfl_xor(red, k, 64);
    if ((t & 63) == 0) sred[t >> 6] = red;
    __syncthreads();
    if (t == 0)   ssrc[i] = sred[0] + sred[1];
    if (t == 128) sdst[i] = sred[2] + sred[3];
  } else if (b == N) {
    if (t < DE) {
      float s = 0.f;
      for (int o = 0; o < DOUT; ++o) s += A[o * AROW + 2 * DIN + t] * a2[o];
      wv[t] = s;
    }
  } else if (b <= N + DOUT) {
    int o = b - (N + 1);
    if (t < DE) Bcat[o * BK + KP + t] = f2bf(A[o * AROW + 2 * DIN + t]);
    if (t < KP - N) Bcat[o * BK + N + t] = 0;                                 // j-pad
    if (t >= 32 && t < 32 + (BK - KP - DE)) Bcat[o * BK + KP + DE + (t - 32)] = 0; // d-pad
  } else if (b <= 702) {
    int off = (b - 601) * 1024 + t * 4;
    if (off < GZF) *(float4*)(gsum + off) = make_float4(0.f, 0.f, 0.f, 0.f);
  } else {
    if (t < 125) *(float4*)(Zsum + t * 4) = make_float4(0.f, 0.f, 0.f, 0.f);
  }
}

// ---------- K2: streaming pass, group-per-row gather + NON-TEMPORAL E loads ----------
__global__ __launch_bounds__(256, 4)
void passA(const float* __restrict__ E, const int* __restrict__ adj,
           const float* __restrict__ ssrcA, const float* __restrict__ sdstA,
           const float* __restrict__ wv,
           unsigned short* __restrict__ Pbuf,
           float* __restrict__ gsum, float* __restrict__ Zsum) {
  __shared__ int   list[CROWS + 8];
  __shared__ float bias[CROWS + 8];     // ssrc_i + sdst[j] per compacted slot
  __shared__ int cntS;
  __shared__ float gl[4][200];
  __shared__ float zl[4];

  int bid = blockIdx.x;
  int i = bid >> 1, c = bid & 1;
  int jbeg = c * CROWS;
  int t = threadIdx.x, wid = t >> 6, lane = t & 63;
  int ll = lane & 31;                   // lane-in-group
  int grp = lane >> 5;                  // 0 = row A, 1 = row B

  if (t == 0) cntS = 0;
  __syncthreads();

  float ssrc_i = ssrcA[i];
  // ballot-compact active j's; write p=0 for inactive
  bool active = false;
  if (t < CROWS) active = (adj[(size_t)i * N + jbeg + t] > 0);
  unsigned long long mask = __ballot(active);
  int wbase = 0;
  if (lane == 0 && mask) wbase = atomicAdd(&cntS, __popcll(mask));
  wbase = __shfl(wbase, 0);
  if (active) {
    int slot = wbase + __popcll(mask & ((1ull << lane) - 1ull));
    list[slot] = jbeg + t;
    bias[slot] = ssrc_i + sdstA[jbeg + t];
  } else if (t < CROWS) {
    __builtin_nontemporal_store((unsigned short)0, &Pbuf[i * KP + jbeg + t]);
  }
  __syncthreads();
  int cnt = cntS;
  int cnt_pad = (cnt + 7) & ~7;
  // pad with sentinels: valid row index, bias -> p = 0
  for (int s = cnt + t; s < cnt_pad; s += 256) { list[s] = jbeg; bias[s] = -1e30f; }
  __syncthreads();

  // per-lane w slice: elems [8ll .. 8ll+7]
  float4 wa = make_float4(0.f, 0.f, 0.f, 0.f), wb = wa;
  if (ll < 25) {
    wa = *(const float4*)(wv + ll * 8);
    wb = *(const float4*)(wv + ll * 8 + 4);
  }

  float g1x = 0.f, g1y = 0.f, g1z = 0.f, g1w = 0.f;   // elems 8ll+0..3
  float g2x = 0.f, g2y = 0.f, g2z = 0.f, g2w = 0.f;   // elems 8ll+4..7
  float Z = 0.f;
  const float* Erow = E + (size_t)i * N * DE;

  // main: 8 slots (4 row-pairs) per wave per iteration
  for (int base = wid * 8; base < cnt_pad; base += 32) {
    #pragma unroll
    for (int r = 0; r < 4; ++r) {
      int slot = base + 2 * r + grp;                  // per-lane: group picks row
      int j = list[slot];
      float bi = bias[slot];
      f32x4 ev1 = {0.f, 0.f, 0.f, 0.f}, ev2 = {0.f, 0.f, 0.f, 0.f};
      if (ll < 25) {
        const f32x4* rp = (const f32x4*)(Erow + (size_t)j * DE + ll * 8);
        ev1 = __builtin_nontemporal_load(rp);         // zero-reuse stream: bypass L2/L3
        ev2 = __builtin_nontemporal_load(rp + 1);
      }
      float d = ev1[0] * wa.x + ev1[1] * wa.y + ev1[2] * wa.z + ev1[3] * wa.w
              + ev2[0] * wb.x + ev2[1] * wb.y + ev2[2] * wb.z + ev2[3] * wb.w;
      d += __shfl_xor(d, 1);  d += __shfl_xor(d, 2);  d += __shfl_xor(d, 4);
      d += __shfl_xor(d, 8);  d += __shfl_xor(d, 16);      // uniform within group
      float s = bi + d;
      s = s > 0.f ? s : SLOPE * s;
      float p = __expf(s);                                 // 0 for sentinel slots
      Z += p;
      g1x += p * ev1[0]; g1y += p * ev1[1]; g1z += p * ev1[2]; g1w += p * ev1[3];
      g2x += p * ev2[0]; g2y += p * ev2[1]; g2z += p * ev2[2]; g2w += p * ev2[3];
      if (ll == 0 && slot < cnt) __builtin_nontemporal_store(f2bf(p), &Pbuf[i * KP + j]);
    }
  }

  // merge the two groups (A+B) once
  g1x += __shfl_xor(g1x, 32); g1y += __shfl_xor(g1y, 32);
  g1z += __shfl_xor(g1z, 32); g1w += __shfl_xor(g1w, 32);
  g2x += __shfl_xor(g2x, 32); g2y += __shfl_xor(g2y, 32);
  g2z += __shfl_xor(g2z, 32); g2w += __shfl_xor(g2w, 32);
  Z += __shfl_xor(Z, 32);

  if (lane < 25) {
    float* gp = &gl[wid][lane * 8];
    gp[0] = g1x; gp[1] = g1y; gp[2] = g1z; gp[3] = g1w;
    gp[4] = g2x; gp[5] = g2y; gp[6] = g2z; gp[7] = g2w;
  }
  if (lane == 0) zl[wid] = Z;
  __syncthreads();
  if (t < 200) {
    float s = gl[0][t] + gl[1][t] + gl[2][t] + gl[3][t];
    atomicAdd(gsum + (size_t)i * DEP + t, s);
  }
  if (t == 200) atomicAdd(Zsum + i, zl[0] + zl[1] + zl[2] + zl[3]);
}

// ---------- K3: combine — [P | g] @ [dst ; a_ent^T] via MFMA (dual acc chains) ----------
__global__ __launch_bounds__(64)
void combine_kernel(const float* __restrict__ src,
                    const unsigned short* __restrict__ Pbuf,
                    const unsigned short* __restrict__ Bcat,
                    const float* __restrict__ gsum,
                    const float* __restrict__ Zsum,
                    float* __restrict__ out) {
  int b = blockIdx.x;
  int i0 = (b >> 2) * 32;
  int ow = b & 3;
  int t = threadIdx.x;                  // 0..63
  int c31 = t & 31, hi = t >> 5;
  int o = ow * 32 + c31;
  int arow = i0 + c31; if (arow > N - 1) arow = N - 1;

  const unsigned short* Prow = Pbuf + (size_t)arow * KP;
  const float* grow = gsum + (size_t)arow * DEP;

  f32x16 acc0 = {}, acc1 = {};
  #pragma unroll
  for (int ks = 0; ks < 45; ++ks) {
    short8 a, bf;
    if (ks < 32) {
      a = *(const short8*)(Prow + ks * 16 + hi * 8);
    } else {
      int d0 = (ks - 32) * 16 + hi * 8;
      float4 ga = *(const float4*)(grow + d0);
      float4 gb = *(const float4*)(grow + d0 + 4);
      a[0] = (short)f2bf(ga.x); a[1] = (short)f2bf(ga.y);
      a[2] = (short)f2bf(ga.z); a[3] = (short)f2bf(ga.w);
      a[4] = (short)f2bf(gb.x); a[5] = (short)f2bf(gb.y);
      a[6] = (short)f2bf(gb.z); a[7] = (short)f2bf(gb.w);
    }
    if (o < DOUT) bf = *(const short8*)(Bcat + (size_t)o * BK + ks * 16 + hi * 8);
    else { short8 zz = {}; bf = zz; }
    if (ks & 1) acc1 = __builtin_amdgcn_mfma_f32_32x32x16_bf16(a, bf, acc1, 0, 0, 0);
    else        acc0 = __builtin_amdgcn_mfma_f32_32x32x16_bf16(a, bf, acc0, 0, 0, 0);
  }

  if (o < DOUT) {
    #pragma unroll
    for (int r = 0; r < 16; ++r) {
      int row = (r & 3) + 8 * (r >> 2) + 4 * hi;
      int i = i0 + row;
      if (i < N) {
        float h = src[i * DOUT + o] + (acc0[r] + acc1[r]) / Zsum[i];
        out[i * DOUT + o] = h > 0.f ? h : expm1f(h);
      }
    }
  }
}

extern "C" void kernel_launch(void* const* d_in, const int* in_sizes, int n_in,
                              void* d_out, int out_size, void* d_ws, size_t ws_size,
                              hipStream_t stream) {
  const float* R   = (const float*)d_in[0];
  const float* E   = (const float*)d_in[1];
  const int*   adj = (const int*)d_in[2];
  const float* A   = (const float*)d_in[3];
  const float* a2  = (const float*)d_in[4];
  float* out = (float*)d_out;

  char* wsb = (char*)d_ws;
  float*          src  = (float*)(wsb + 0);                // 200,000 B
  float*          ssrc = (float*)(wsb + 200000);           //   2,000 B
  float*          sdst = (float*)(wsb + 202000);           //   2,000 B
  float*          wv   = (float*)(wsb + 204000);           //     800 B
  unsigned short* Bcat = (unsigned short*)(wsb + 204800);  // 144,000 B
  unsigned short* Pbuf = (unsigned short*)(wsb + 348800);  // 512,000 B
  float*          gsum = (float*)(wsb + 860800);           // 416,000 B (f32, atomic)
  float*          Zsum = (float*)(wsb + 1276800);          //   2,000 B

  setup_kernel<<<704, 256, 0, stream>>>(R, A, a2, src, ssrc, sdst, wv, Bcat, Pbuf, gsum, Zsum);
  passA<<<N * JCH, 256, 0, stream>>>(E, adj, ssrc, sdst, wv, Pbuf, gsum, Zsum);
  combine_kernel<<<64, 64, 0, stream>>>(src, Pbuf, Bcat, gsum, Zsum, out);
}

// Round 16
// 53.666 us; speedup vs baseline: 1.1876x; 1.1011x over previous
//
#include <hip/hip_runtime.h>
#include <stdint.h>
#include <math.h>

#define N     500
#define DIN   100
#define DE    200
#define DOUT  100
#define AROW  (2*DIN + DE)        // 400
#define SLOPE 0.2f

#define JCH   2                   // j-chunks per row i
#define CROWS 250                 // 500 / 2
#define KP    512                 // Pbuf padded row length (j)
#define BK    720                 // Bcat row length: 512 (j) + 208 (d pad)
#define DEP   208                 // padded DE (f32 gpart stride)

typedef __attribute__((ext_vector_type(8)))  short short8;
typedef __attribute__((ext_vector_type(16))) float f32x16;

static __device__ __forceinline__ unsigned short f2bf(float f) {
  union { float f; uint32_t u; } v; v.f = f;
  uint32_t r = (v.u + 0x7FFFu + ((v.u >> 16) & 1u)) >> 16;   // RNE
  return (unsigned short)r;
}

// ---------- K1: merged setup ----------
__global__ __launch_bounds__(256)
void setup_kernel(const float* __restrict__ R, const float* __restrict__ A,
                  const float* __restrict__ a2,
                  float* __restrict__ src, float* __restrict__ ssrc,
                  float* __restrict__ sdst, float* __restrict__ wv,
                  unsigned short* __restrict__ Bcat, unsigned short* __restrict__ Pbuf) {
  int b = blockIdx.x, t = threadIdx.x;
  if (b < N) {
    int i = b;
    __shared__ float rrow[DIN];
    __shared__ float sred[4];
    if (t < DIN) rrow[t] = R[i * DIN + t];
    if (t < KP - N) Pbuf[i * KP + N + t] = 0;          // zero j-pad 500..511
    __syncthreads();
    int o = -1; bool isSrc = false;
    if (t < DOUT) { o = t; isSrc = true; }
    else if (t >= 128 && t < 128 + DOUT) { o = t - 128; }
    float val = 0.f;
    if (o >= 0) {
      const float* arow = A + o * AROW + (isSrc ? 0 : DIN);
      #pragma unroll 4
      for (int d = 0; d < DIN; ++d) val += rrow[d] * arow[d];
      if (isSrc) src[i * DOUT + o] = val;
      else       Bcat[o * BK + i] = f2bf(val);         // B[k=j=i][n=o] = dst[j,o]
    }
    float red = (o >= 0) ? val * a2[o] : 0.f;
    #pragma unroll
    for (int k = 1; k < 64; k <<= 1) red += __shfl_xor(red, k, 64);
    if ((t & 63) == 0) sred[t >> 6] = red;
    __syncthreads();
    if (t == 0)   ssrc[i] = sred[0] + sred[1];
    if (t == 128) sdst[i] = sred[2] + sred[3];
  } else if (b == N) {
    if (t < DE) {
      float s = 0.f;
      for (int o = 0; o < DOUT; ++o) s += A[o * AROW + 2 * DIN + t] * a2[o];
      wv[t] = s;
    }
  } else {
    int o = b - (N + 1);
    if (t < DE) Bcat[o * BK + KP + t] = f2bf(A[o * AROW + 2 * DIN + t]);
    if (t < KP - N) Bcat[o * BK + N + t] = 0;                                 // j-pad
    if (t >= 32 && t < 32 + (BK - KP - DE)) Bcat[o * BK + KP + DE + (t - 32)] = 0; // d-pad
  }
}

// ---------- K2: streaming pass, row-pair-per-wave (group-per-row), plain-store partials ----------
__global__ __launch_bounds__(256, 4)
void passA(const float* __restrict__ E, const int* __restrict__ adj,
           const float* __restrict__ ssrcA, const float* __restrict__ sdstA,
           const float* __restrict__ wv,
           unsigned short* __restrict__ Pbuf,
           float* __restrict__ gpart, float* __restrict__ Zpart) {
  __shared__ int   list[CROWS + 8];
  __shared__ float bias[CROWS + 8];     // ssrc_i + sdst[j] per compacted slot
  __shared__ int cntS;
  __shared__ float gl[4][200];
  __shared__ float zl[4];

  int bid = blockIdx.x;
  int i = bid >> 1, c = bid & 1;
  int jbeg = c * CROWS;
  int t = threadIdx.x, wid = t >> 6, lane = t & 63;
  int ll = lane & 31;                   // lane-in-group
  int grp = lane >> 5;                  // 0 = row A, 1 = row B

  if (t == 0) cntS = 0;
  __syncthreads();

  float ssrc_i = ssrcA[i];
  // ballot-compact active j's; write p=0 for inactive
  bool active = false;
  if (t < CROWS) active = (adj[(size_t)i * N + jbeg + t] > 0);
  unsigned long long mask = __ballot(active);
  int wbase = 0;
  if (lane == 0 && mask) wbase = atomicAdd(&cntS, __popcll(mask));
  wbase = __shfl(wbase, 0);
  if (active) {
    int slot = wbase + __popcll(mask & ((1ull << lane) - 1ull));
    list[slot] = jbeg + t;
    bias[slot] = ssrc_i + sdstA[jbeg + t];
  } else if (t < CROWS) {
    Pbuf[i * KP + jbeg + t] = 0;
  }
  __syncthreads();
  int cnt = cntS;
  int cnt_pad = (cnt + 7) & ~7;
  // pad with sentinels: valid row index, bias -> p = 0
  for (int s = cnt + t; s < cnt_pad; s += 256) { list[s] = jbeg; bias[s] = -1e30f; }
  __syncthreads();

  // per-lane w slice: elems [8ll .. 8ll+7]
  float4 wa = make_float4(0.f, 0.f, 0.f, 0.f), wb = wa;
  if (ll < 25) {
    wa = *(const float4*)(wv + ll * 8);
    wb = *(const float4*)(wv + ll * 8 + 4);
  }

  float g1x = 0.f, g1y = 0.f, g1z = 0.f, g1w = 0.f;   // elems 8ll+0..3
  float g2x = 0.f, g2y = 0.f, g2z = 0.f, g2w = 0.f;   // elems 8ll+4..7
  float Z = 0.f;
  const float* Erow = E + (size_t)i * N * DE;

  // main: 8 slots (4 row-pairs) per wave per iteration
  for (int base = wid * 8; base < cnt_pad; base += 32) {
    #pragma unroll
    for (int r = 0; r < 4; ++r) {
      int slot = base + 2 * r + grp;                  // per-lane: group picks row
      int j = list[slot];
      float bi = bias[slot];
      float4 ev1 = make_float4(0.f, 0.f, 0.f, 0.f), ev2 = ev1;
      if (ll < 25) {
        const float* rp = Erow + (size_t)j * DE + ll * 8;
        ev1 = *(const float4*)(rp);
        ev2 = *(const float4*)(rp + 4);
      }
      float d = ev1.x * wa.x + ev1.y * wa.y + ev1.z * wa.z + ev1.w * wa.w
              + ev2.x * wb.x + ev2.y * wb.y + ev2.z * wb.z + ev2.w * wb.w;
      d += __shfl_xor(d, 1);  d += __shfl_xor(d, 2);  d += __shfl_xor(d, 4);
      d += __shfl_xor(d, 8);  d += __shfl_xor(d, 16);      // uniform within group
      float s = bi + d;
      s = s > 0.f ? s : SLOPE * s;
      float p = __expf(s);                                 // 0 for sentinel slots
      Z += p;
      g1x += p * ev1.x; g1y += p * ev1.y; g1z += p * ev1.z; g1w += p * ev1.w;
      g2x += p * ev2.x; g2y += p * ev2.y; g2z += p * ev2.z; g2w += p * ev2.w;
      if (ll == 0 && slot < cnt) Pbuf[i * KP + j] = f2bf(p);
    }
  }

  // merge the two groups (A+B) once
  g1x += __shfl_xor(g1x, 32); g1y += __shfl_xor(g1y, 32);
  g1z += __shfl_xor(g1z, 32); g1w += __shfl_xor(g1w, 32);
  g2x += __shfl_xor(g2x, 32); g2y += __shfl_xor(g2y, 32);
  g2z += __shfl_xor(g2z, 32); g2w += __shfl_xor(g2w, 32);
  Z += __shfl_xor(Z, 32);

  if (lane < 25) {
    float* gp = &gl[wid][lane * 8];
    gp[0] = g1x; gp[1] = g1y; gp[2] = g1z; gp[3] = g1w;
    gp[4] = g2x; gp[5] = g2y; gp[6] = g2z; gp[7] = g2w;
  }
  if (lane == 0) zl[wid] = Z;
  __syncthreads();
  if (t < 200) {
    float s = gl[0][t] + gl[1][t] + gl[2][t] + gl[3][t];
    gpart[(size_t)(i * JCH + c) * DEP + t] = s;          // plain store, no atomic
  } else if (t < DEP) {
    gpart[(size_t)(i * JCH + c) * DEP + t] = 0.f;        // zero the pad: ws garbage may be NaN
  } else if (t == DEP) {
    Zpart[i * JCH + c] = zl[0] + zl[1] + zl[2] + zl[3];
  }
}

// ---------- K3: combine — [P | g] @ [dst ; a_ent^T] via MFMA (dual acc chains) ----------
__global__ __launch_bounds__(64)
void combine_kernel(const float* __restrict__ src,
                    const unsigned short* __restrict__ Pbuf,
                    const unsigned short* __restrict__ Bcat,
                    const float* __restrict__ gpart,
                    const float* __restrict__ Zpart,
                    float* __restrict__ out) {
  int b = blockIdx.x;
  int i0 = (b >> 2) * 32;
  int ow = b & 3;
  int t = threadIdx.x;                  // 0..63
  int c31 = t & 31, hi = t >> 5;
  int o = ow * 32 + c31;
  int arow = i0 + c31; if (arow > N - 1) arow = N - 1;

  const unsigned short* Prow = Pbuf + (size_t)arow * KP;
  const float* g0row = gpart + (size_t)(arow * JCH + 0) * DEP;
  const float* g1row = gpart + (size_t)(arow * JCH + 1) * DEP;

  // ALL 64 lanes compute Zrow (it feeds a cross-lane shuffle below;
  // computing it under `if (o < DOUT)` left source lanes undefined — R14/R15 bug)
  float Zrow = Zpart[arow * JCH] + Zpart[arow * JCH + 1];

  f32x16 acc0 = {}, acc1 = {};
  #pragma unroll
  for (int ks = 0; ks < 45; ++ks) {
    short8 a, bf;
    if (ks < 32) {
      a = *(const short8*)(Prow + ks * 16 + hi * 8);
    } else {
      int d0 = (ks - 32) * 16 + hi * 8;
      float4 ga = *(const float4*)(g0row + d0);
      float4 gb = *(const float4*)(g0row + d0 + 4);
      float4 ha = *(const float4*)(g1row + d0);
      float4 hb = *(const float4*)(g1row + d0 + 4);
      a[0] = (short)f2bf(ga.x + ha.x); a[1] = (short)f2bf(ga.y + ha.y);
      a[2] = (short)f2bf(ga.z + ha.z); a[3] = (short)f2bf(ga.w + ha.w);
      a[4] = (short)f2bf(gb.x + hb.x); a[5] = (short)f2bf(gb.y + hb.y);
      a[6] = (short)f2bf(gb.z + hb.z); a[7] = (short)f2bf(gb.w + hb.w);
    }
    if (o < DOUT) bf = *(const short8*)(Bcat + (size_t)o * BK + ks * 16 + hi * 8);
    else { short8 zz = {}; bf = zz; }
    if (ks & 1) acc1 = __builtin_amdgcn_mfma_f32_32x32x16_bf16(a, bf, acc1, 0, 0, 0);
    else        acc0 = __builtin_amdgcn_mfma_f32_32x32x16_bf16(a, bf, acc0, 0, 0, 0);
  }

  #pragma unroll
  for (int r = 0; r < 16; ++r) {
    int row = (r & 3) + 8 * (r >> 2) + 4 * hi;
    float Zi = __shfl(Zrow, row, 32);   // all lanes participate
    int i = i0 + row;
    if (o < DOUT && i < N) {
      float h = src[i * DOUT + o] + (acc0[r] + acc1[r]) / Zi;
      out[i * DOUT + o] = h > 0.f ? h : expm1f(h);
    }
  }
}

extern "C" void kernel_launch(void* const* d_in, const int* in_sizes, int n_in,
                              void* d_out, int out_size, void* d_ws, size_t ws_size,
                              hipStream_t stream) {
  const float* R   = (const float*)d_in[0];
  const float* E   = (const float*)d_in[1];
  const int*   adj = (const int*)d_in[2];
  const float* A   = (const float*)d_in[3];
  const float* a2  = (const float*)d_in[4];
  float* out = (float*)d_out;

  char* wsb = (char*)d_ws;
  float*          src   = (float*)(wsb + 0);                // 200,000 B
  float*          ssrc  = (float*)(wsb + 200000);           //   2,000 B
  float*          sdst  = (float*)(wsb + 202000);           //   2,000 B
  float*          wv    = (float*)(wsb + 204000);           //     800 B
  unsigned short* Bcat  = (unsigned short*)(wsb + 204800);  // 144,000 B
  unsigned short* Pbuf  = (unsigned short*)(wsb + 348800);  // 512,000 B
  float*          gpart = (float*)(wsb + 860800);           // 832,000 B (2 slices)
  float*          Zpart = (float*)(wsb + 1692800);          //   4,000 B

  setup_kernel<<<N + 1 + DOUT, 256, 0, stream>>>(R, A, a2, src, ssrc, sdst, wv, Bcat, Pbuf);
  passA<<<N * JCH, 256, 0, stream>>>(E, adj, ssrc, sdst, wv, Pbuf, gpart, Zpart);
  combine_kernel<<<64, 64, 0, stream>>>(src, Pbuf, Bcat, gpart, Zpart, out);
}